// Round 2
// baseline (279.159 us; speedup 1.0000x reference)
//
#include <hip/hip_runtime.h>
#include <stdint.h>

typedef short s16x8 __attribute__((ext_vector_type(8)));
typedef float f32x4 __attribute__((ext_vector_type(4)));

#define AS1 __attribute__((address_space(1)))
#define AS3 __attribute__((address_space(3)))

static constexpr int Bc = 2, Tc = 2048, NXc = 1024, Hc = 16;
static constexpr float NEGC = -1e9f;

static __device__ __forceinline__ unsigned short f2bf(float f) {
  uint32_t u = __builtin_bit_cast(uint32_t, f);
  u += 0x7fffu + ((u >> 16) & 1u);
  return (unsigned short)(u >> 16);
}

static __device__ __forceinline__ void gload_lds16(const void* g, void* l) {
  __builtin_amdgcn_global_load_lds((const AS1 uint32_t*)g, (AS3 uint32_t*)l, 16, 0, 0);
}

// ---------------- prep: x -> bf16 ----------------
__global__ __launch_bounds__(256) void k_cvt_x(const float* __restrict__ x,
                                               unsigned short* __restrict__ xb) {
  int i = blockIdx.x * blockDim.x + threadIdx.x;  // one float4 each, grid exact
  float4 v = ((const float4*)x)[i];
  uint32_t lo = (uint32_t)f2bf(v.x) | ((uint32_t)f2bf(v.y) << 16);
  uint32_t hi = (uint32_t)f2bf(v.z) | ((uint32_t)f2bf(v.w) << 16);
  ((uint2*)xb)[i] = make_uint2(lo, hi);
}

// ---------------- prep: transpose f32 [K][N] -> bf16 [N][dld] at col offset dkoff ----
__global__ __launch_bounds__(256) void k_transpose_bf16(
    const float* __restrict__ src, int srows, int scols,
    unsigned short* __restrict__ dst, int dld, int dkoff) {
  __shared__ float tile[32][33];
  int n0 = blockIdx.x * 32, k0 = blockIdx.y * 32;
  int tx = threadIdx.x & 31, ty = threadIdx.x >> 5;  // 32 x 8
#pragma unroll
  for (int r = 0; r < 4; r++)
    tile[ty + r * 8][tx] = src[(size_t)(k0 + ty + r * 8) * scols + n0 + tx];
  __syncthreads();
#pragma unroll
  for (int r = 0; r < 4; r++) {
    int n = n0 + ty + r * 8;
    dst[(size_t)n * dld + dkoff + k0 + tx] = f2bf(tile[tx][ty + r * 8]);
  }
}

// ---------------- prep: adjacency tile classifier ----------------
// tm[qt*64 + kt]: 0 = all zero (skip), 1 = mixed (apply mask), 2 = all exactly 1.0 (no mask)
__global__ __launch_bounds__(256) void k_tilemask(const float* __restrict__ adj,
                                                  unsigned char* __restrict__ tm) {
  int kt = blockIdx.x, qt = blockIdx.y;
  int t = threadIdx.x;
  bool anyv = false, all1 = true;
#pragma unroll
  for (int i = 0; i < 8; i++) {
    int e = t * 8 + i;  // 64x32 block, row-major
    float v = adj[(size_t)(qt * 64 + (e >> 5)) * Tc + kt * 32 + (e & 31)];
    anyv |= (v != 0.0f);
    all1 &= (v == 1.0f);
  }
  __shared__ int s_any, s_all;
  if (t == 0) { s_any = 0; s_all = 1; }
  __syncthreads();
  if (anyv) s_any = 1;
  if (!all1) s_all = 0;
  __syncthreads();
  if (t == 0) tm[qt * 64 + kt] = (unsigned char)(s_any ? (s_all ? 2 : 1) : 0);
}

// ---------------- bf16 GEMM, B^T layout: C[M][N] = A[M][K] * BT[N][K]^T ----------------
// MODE 0: C -> qkv bf16 [M][3072] (+bias0), and q-part also copied to acat[:,1024+n]
// MODE 1: C -> out f32 [M][1024] (+bias0+bias1)
template <int MODE>
__global__ __launch_bounds__(256) void k_gemm_bt(
    const unsigned short* __restrict__ A, const unsigned short* __restrict__ BT, int K,
    const float* __restrict__ bias0, const float* __restrict__ bias1,
    unsigned short* __restrict__ Cb, unsigned short* __restrict__ Cq,
    float* __restrict__ Cf) {
  __shared__ __align__(16) unsigned short As[128 * 32];
  __shared__ __align__(16) unsigned short Bs[128 * 32];
  const int lane = threadIdx.x & 63;
  const int w = threadIdx.x >> 6;
  const int m0 = blockIdx.y * 128;
  const int n0 = blockIdx.x * 128;
  const int wr = (w >> 1) * 64;
  const int wc = (w & 1) * 64;
  const int g = lane >> 4, lr = lane & 15;
  const int srow = lane >> 2;   // row within 16-row chunk
  const int scol = lane & 3;    // 16B column slot within row
  f32x4 acc[4][4] = {};

  for (int k0 = 0; k0 < K; k0 += 32) {
    __syncthreads();
#pragma unroll
    for (int i = 0; i < 2; i++) {
      int c = w * 2 + i;                 // chunk 0..7 (16 rows, 1KB each)
      int row = c * 16 + srow;
      int cs = scol ^ (row & 3);         // pre-swizzled global source (G21)
      gload_lds16(A + (size_t)(m0 + row) * K + k0 + cs * 8, (void*)(As + c * 512));
      gload_lds16(BT + (size_t)(n0 + row) * K + k0 + cs * 8, (void*)(Bs + c * 512));
    }
    __syncthreads();
    s16x8 af[4], bfr[4];
#pragma unroll
    for (int m = 0; m < 4; m++) {
      int row = wr + m * 16 + lr;
      af[m] = *(const s16x8*)((const char*)As + row * 64 + ((g ^ (row & 3)) * 16));
    }
#pragma unroll
    for (int n = 0; n < 4; n++) {
      int row = wc + n * 16 + lr;
      bfr[n] = *(const s16x8*)((const char*)Bs + row * 64 + ((g ^ (row & 3)) * 16));
    }
#pragma unroll
    for (int m = 0; m < 4; m++)
#pragma unroll
      for (int n = 0; n < 4; n++)
        acc[m][n] = __builtin_amdgcn_mfma_f32_16x16x32_bf16(af[m], bfr[n], acc[m][n], 0, 0, 0);
  }

#pragma unroll
  for (int m = 0; m < 4; m++) {
    int row = m0 + wr + m * 16 + g * 4;  // + jj
#pragma unroll
    for (int n = 0; n < 4; n++) {
      int col = n0 + wc + n * 16 + lr;
      if (MODE == 0) {
        float bs = bias0[col];
#pragma unroll
        for (int jj = 0; jj < 4; jj++) {
          unsigned short h = f2bf(acc[m][n][jj] + bs);
          Cb[(size_t)(row + jj) * 3072 + col] = h;
          if (col < NXc) Cq[(size_t)(row + jj) * 2048 + NXc + col] = h;  // q copy for residue GEMM
        }
      } else {
        float bs = bias0[col] + bias1[col];
#pragma unroll
        for (int jj = 0; jj < 4; jj++)
          Cf[(size_t)(row + jj) * NXc + col] = acc[m][n][jj] + bs;
      }
    }
  }
}

// ---------------- flash attention: 64 q-rows/block, 4 waves x 16 rows, KVBLK=32 ----------------
__global__ __launch_bounds__(256) void k_attn(
    const unsigned short* __restrict__ qkv,  // [4096][3072] bf16 (q|k|v)
    const float* __restrict__ adj,           // [2048][2048]
    const unsigned char* __restrict__ tm,    // [32][64]
    unsigned short* __restrict__ acat) {     // [4096][2048] bf16, cols 0..1023 written here
  __shared__ __align__(16) unsigned short Ks[32 * 64];  // [kv][d], 16B-granule XOR swizzle
  __shared__ __align__(16) unsigned short Vt[2608];     // byte(d,kv) = d*80 + (d>>3)*16 + 2*kv
  __shared__ __align__(16) unsigned short Ps[4 * 16 * 40];  // per-wave P [16][40] padded

  const int bid = blockIdx.x;
  const int qt = bid & 31;
  const int h = (bid >> 5) & 15;
  const int b = bid >> 9;
  const int q0 = qt * 64;
  const int lane = threadIdx.x & 63;
  const int w = threadIdx.x >> 6;
  const int g = lane >> 4, lr = lane & 15;

  // hoist Q fragments (A-operand: row = lane&15, k = 8*(lane>>4)+j)
  s16x8 qf0, qf1;
  {
    size_t base = (size_t)(b * Tc + q0 + w * 16 + lr) * 3072 + h * 64 + g * 8;
    qf0 = *(const s16x8*)(qkv + base);
    qf1 = *(const s16x8*)(qkv + base + 32);
  }
  f32x4 o[4] = {};
  float mrow[4], lrow[4];
#pragma unroll
  for (int jj = 0; jj < 4; jj++) { mrow[jj] = -__builtin_inff(); lrow[jj] = 0.f; }

  const int sdc = threadIdx.x & 7;   // staging d-chunk
  const int skv = threadIdx.x >> 3;  // staging kv row 0..31
  const unsigned char* tmrow = tm + qt * 64;

  for (int kt = 0; kt < 64; kt++) {
    const int tmv = tmrow[kt];
    if (tmv == 0) continue;  // uniform across block
    const int kv0 = kt * 32;
    __syncthreads();
    {  // stage K (swizzled b128 write) and V (transposed, padded-stride scalar writes)
      size_t gb = (size_t)(b * Tc + kv0 + skv) * 3072 + 1024 + h * 64 + sdc * 8;
      s16x8 kvec = *(const s16x8*)(qkv + gb);
      *(s16x8*)((char*)Ks + skv * 128 + ((sdc ^ (skv & 7)) * 16)) = kvec;
      s16x8 vvec = *(const s16x8*)(qkv + gb + 1024);
#pragma unroll
      for (int j = 0; j < 8; j++) {
        int d = sdc * 8 + j;
        Vt[(d * 80 + sdc * 16 + 2 * skv) >> 1] = (unsigned short)vvec[j];
      }
    }
    __syncthreads();

    // S = Q K^T  (two 16-col fragments, D=64 as two K=32 steps)
    f32x4 s[2];
#pragma unroll
    for (int n = 0; n < 2; n++) {
      int kvr = n * 16 + lr;
      s16x8 b0 = *(const s16x8*)((const char*)Ks + kvr * 128 + ((g ^ (kvr & 7)) * 16));
      s16x8 b1 = *(const s16x8*)((const char*)Ks + kvr * 128 + (((4 + g) ^ (kvr & 7)) * 16));
      f32x4 z = {};
      z = __builtin_amdgcn_mfma_f32_16x16x32_bf16(qf0, b0, z, 0, 0, 0);
      s[n] = __builtin_amdgcn_mfma_f32_16x16x32_bf16(qf1, b1, z, 0, 0, 0);
    }
    if (tmv != 2) {
      // mixed tile: ref formula w = s*adj + NEG*(1-adj), computed EXACTLY this way.
      // (NOT a*(s-NEG)+NEG: that computes (s+1e9)-1e9 for a==1, and f32 ulp at 1e9
      //  is 64 -> every unmasked score |s|<32 rounds to 0. That was round-1's bug.)
      // tmv!=2 (not ==1): garbage tm degrades to correct-but-slower full masking.
#pragma unroll
      for (int n = 0; n < 2; n++) {
        int col = kv0 + n * 16 + lr;
#pragma unroll
        for (int jj = 0; jj < 4; jj++) {
          float a = adj[(size_t)(q0 + w * 16 + g * 4 + jj) * Tc + col];
          s[n][jj] = a * s[n][jj] + NEGC * (1.0f - a);
        }
      }
    }

    // online softmax, wave-parallel over the 16-lane col groups
    float pf[2][4];
#pragma unroll
    for (int jj = 0; jj < 4; jj++) {
      float mx = fmaxf(s[0][jj], s[1][jj]);
#pragma unroll
      for (int off = 8; off >= 1; off >>= 1) mx = fmaxf(mx, __shfl_xor(mx, off));
      float mn = fmaxf(mrow[jj], mx);
      float rs = __expf(mrow[jj] - mn);
      mrow[jj] = mn;
      float p0 = __expf(s[0][jj] - mn);
      float p1 = __expf(s[1][jj] - mn);
      pf[0][jj] = p0; pf[1][jj] = p1;
      float ps = p0 + p1;
#pragma unroll
      for (int off = 8; off >= 1; off >>= 1) ps += __shfl_xor(ps, off);
      lrow[jj] = lrow[jj] * rs + ps;
#pragma unroll
      for (int nd = 0; nd < 4; nd++) o[nd][jj] *= rs;
    }

    // P -> LDS (bf16), then PV
    unsigned short* pw = Ps + w * 640;
#pragma unroll
    for (int n = 0; n < 2; n++)
#pragma unroll
      for (int jj = 0; jj < 4; jj++)
        pw[(g * 4 + jj) * 40 + n * 16 + lr] = f2bf(pf[n][jj]);
    s16x8 pa = *(const s16x8*)((const char*)Ps + w * 1280 + lr * 80 + g * 16);
#pragma unroll
    for (int nd = 0; nd < 4; nd++) {
      int d = nd * 16 + lr;
      s16x8 vb = *(const s16x8*)((const char*)Vt + d * 80 + (d >> 3) * 16 + g * 16);
      o[nd] = __builtin_amdgcn_mfma_f32_16x16x32_bf16(pa, vb, o[nd], 0, 0, 0);
    }
  }

#pragma unroll
  for (int jj = 0; jj < 4; jj++) {
    float inv = lrow[jj] > 0.f ? 1.0f / lrow[jj] : 0.f;
    size_t m = (size_t)(b * Tc + q0 + w * 16 + g * 4 + jj);
#pragma unroll
    for (int nd = 0; nd < 4; nd++)
      acat[m * 2048 + h * 64 + nd * 16 + lr] = f2bf(o[nd][jj] * inv);
  }
}

extern "C" void kernel_launch(void* const* d_in, const int* in_sizes, int n_in,
                              void* d_out, int out_size, void* d_ws, size_t ws_size,
                              hipStream_t stream) {
  const float* x       = (const float*)d_in[0];
  const float* adj     = (const float*)d_in[1];
  const float* w_attn  = (const float*)d_in[2];
  const float* b_attn  = (const float*)d_in[3];
  const float* w_proj  = (const float*)d_in[4];
  const float* b_proj  = (const float*)d_in[5];
  const float* w_proj1 = (const float*)d_in[6];
  const float* b_proj1 = (const float*)d_in[7];
  float* out = (float*)d_out;

  char* ws = (char*)d_ws;
  size_t off = 0;
  unsigned short* xb     = (unsigned short*)(ws + off); off += (size_t)4096 * 1024 * 2;
  unsigned short* wattnT = (unsigned short*)(ws + off); off += (size_t)3072 * 1024 * 2;
  unsigned short* wcatT  = (unsigned short*)(ws + off); off += (size_t)1024 * 2048 * 2;
  unsigned short* qkv    = (unsigned short*)(ws + off); off += (size_t)4096 * 3072 * 2;
  unsigned short* acat   = (unsigned short*)(ws + off); off += (size_t)4096 * 2048 * 2;
  unsigned char*  tmask  = (unsigned char*)(ws + off);  off += 2048;
  (void)ws_size; (void)in_sizes; (void)n_in; (void)out_size;

  // prep
  k_cvt_x<<<4096, 256, 0, stream>>>(x, xb);
  k_transpose_bf16<<<dim3(96, 32), 256, 0, stream>>>(w_attn, 1024, 3072, wattnT, 1024, 0);
  k_transpose_bf16<<<dim3(32, 32), 256, 0, stream>>>(w_proj, 1024, 1024, wcatT, 2048, 0);
  k_transpose_bf16<<<dim3(32, 32), 256, 0, stream>>>(w_proj1, 1024, 1024, wcatT, 2048, 1024);
  k_tilemask<<<dim3(64, 32), 256, 0, stream>>>(adj, tmask);
  // qkv = x @ w_attn + b_attn (also copies q into acat[:,1024:])
  k_gemm_bt<0><<<dim3(24, 32), 256, 0, stream>>>(xb, wattnT, 1024, b_attn, nullptr,
                                                 qkv, acat, nullptr);
  // attention -> acat[:,0:1024]
  k_attn<<<1024, 256, 0, stream>>>(qkv, adj, tmask, acat);
  // out = [a | q] @ [w_proj ; w_proj1] + b_proj + b_proj1
  k_gemm_bt<1><<<dim3(8, 32), 256, 0, stream>>>(acat, wcatT, 2048, b_proj, b_proj1,
                                                nullptr, nullptr, out);
}

// Round 3
// 179.950 us; speedup vs baseline: 1.5513x; 1.5513x over previous
//
#include <hip/hip_runtime.h>
#include <stdint.h>

typedef short s16x8 __attribute__((ext_vector_type(8)));
typedef float f32x4 __attribute__((ext_vector_type(4)));

#define AS1 __attribute__((address_space(1)))
#define AS3 __attribute__((address_space(3)))

static constexpr int Bc = 2, Tc = 2048, NXc = 1024, Hc = 16;
static constexpr float NEGC = -1e9f;

static __device__ __forceinline__ unsigned short f2bf(float f) {
  uint32_t u = __builtin_bit_cast(uint32_t, f);
  u += 0x7fffu + ((u >> 16) & 1u);
  return (unsigned short)(u >> 16);
}

static __device__ __forceinline__ void gload_lds16(const void* g, void* l) {
  __builtin_amdgcn_global_load_lds((const AS1 uint32_t*)g, (AS3 uint32_t*)l, 16, 0, 0);
}

// ---------------- prep: x -> bf16 ----------------
__global__ __launch_bounds__(256) void k_cvt_x(const float* __restrict__ x,
                                               unsigned short* __restrict__ xb) {
  int i = blockIdx.x * blockDim.x + threadIdx.x;
  float4 v = ((const float4*)x)[i];
  uint32_t lo = (uint32_t)f2bf(v.x) | ((uint32_t)f2bf(v.y) << 16);
  uint32_t hi = (uint32_t)f2bf(v.z) | ((uint32_t)f2bf(v.w) << 16);
  ((uint2*)xb)[i] = make_uint2(lo, hi);
}

// ---------------- prep: transpose f32 [K][N] -> bf16 [N][dld] at col offset dkoff ----
__global__ __launch_bounds__(256) void k_transpose_bf16(
    const float* __restrict__ src, int srows, int scols,
    unsigned short* __restrict__ dst, int dld, int dkoff) {
  __shared__ float tile[32][33];
  int n0 = blockIdx.x * 32, k0 = blockIdx.y * 32;
  int tx = threadIdx.x & 31, ty = threadIdx.x >> 5;
#pragma unroll
  for (int r = 0; r < 4; r++)
    tile[ty + r * 8][tx] = src[(size_t)(k0 + ty + r * 8) * scols + n0 + tx];
  __syncthreads();
#pragma unroll
  for (int r = 0; r < 4; r++) {
    int n = n0 + ty + r * 8;
    dst[(size_t)n * dld + dkoff + k0 + tx] = f2bf(tile[tx][ty + r * 8]);
  }
}

// ---------------- prep: adjacency 64x64 tile classifier ----------------
// tm[qt*32 + kt]: 0 = all zero (skip), 1 = mixed (apply mask), 2 = all exactly 1.0
__global__ __launch_bounds__(256) void k_tilemask(const float* __restrict__ adj,
                                                  unsigned char* __restrict__ tm) {
  int kt = blockIdx.x, qt = blockIdx.y;
  int t = threadIdx.x;
  bool anyv = false, all1 = true;
#pragma unroll
  for (int i = 0; i < 4; i++) {
    int e = t * 4 + i;  // float4 granules: 64x64 tile = 1024 float4
    int row = e >> 4, c4 = e & 15;
    float4 v = *(const float4*)&adj[(size_t)(qt * 64 + row) * Tc + kt * 64 + c4 * 4];
    anyv |= (v.x != 0.f) | (v.y != 0.f) | (v.z != 0.f) | (v.w != 0.f);
    all1 &= (v.x == 1.f) & (v.y == 1.f) & (v.z == 1.f) & (v.w == 1.f);
  }
  __shared__ int s_any, s_all;
  if (t == 0) { s_any = 0; s_all = 1; }
  __syncthreads();
  if (anyv) s_any = 1;
  if (!all1) s_all = 0;
  __syncthreads();
  if (t == 0) tm[qt * 32 + kt] = (unsigned char)(s_any ? (s_all ? 2 : 1) : 0);
}

// ---------------- bf16 GEMM, B^T layout (unchanged from round 2) ----------------
template <int MODE>
__global__ __launch_bounds__(256) void k_gemm_bt(
    const unsigned short* __restrict__ A, const unsigned short* __restrict__ BT, int K,
    const float* __restrict__ bias0, const float* __restrict__ bias1,
    unsigned short* __restrict__ Cb, unsigned short* __restrict__ Cq,
    float* __restrict__ Cf) {
  __shared__ __align__(16) unsigned short As[128 * 32];
  __shared__ __align__(16) unsigned short Bs[128 * 32];
  const int lane = threadIdx.x & 63;
  const int w = threadIdx.x >> 6;
  const int m0 = blockIdx.y * 128;
  const int n0 = blockIdx.x * 128;
  const int wr = (w >> 1) * 64;
  const int wc = (w & 1) * 64;
  const int g = lane >> 4, lr = lane & 15;
  const int srow = lane >> 2;
  const int scol = lane & 3;
  f32x4 acc[4][4] = {};

  for (int k0 = 0; k0 < K; k0 += 32) {
    __syncthreads();
#pragma unroll
    for (int i = 0; i < 2; i++) {
      int c = w * 2 + i;
      int row = c * 16 + srow;
      int cs = scol ^ (row & 3);
      gload_lds16(A + (size_t)(m0 + row) * K + k0 + cs * 8, (void*)(As + c * 512));
      gload_lds16(BT + (size_t)(n0 + row) * K + k0 + cs * 8, (void*)(Bs + c * 512));
    }
    __syncthreads();
    s16x8 af[4], bfr[4];
#pragma unroll
    for (int m = 0; m < 4; m++) {
      int row = wr + m * 16 + lr;
      af[m] = *(const s16x8*)((const char*)As + row * 64 + ((g ^ (row & 3)) * 16));
    }
#pragma unroll
    for (int n = 0; n < 4; n++) {
      int row = wc + n * 16 + lr;
      bfr[n] = *(const s16x8*)((const char*)Bs + row * 64 + ((g ^ (row & 3)) * 16));
    }
#pragma unroll
    for (int m = 0; m < 4; m++)
#pragma unroll
      for (int n = 0; n < 4; n++)
        acc[m][n] = __builtin_amdgcn_mfma_f32_16x16x32_bf16(af[m], bfr[n], acc[m][n], 0, 0, 0);
  }

#pragma unroll
  for (int m = 0; m < 4; m++) {
    int row = m0 + wr + m * 16 + g * 4;
#pragma unroll
    for (int n = 0; n < 4; n++) {
      int col = n0 + wc + n * 16 + lr;
      if (MODE == 0) {
        float bs = bias0[col];
#pragma unroll
        for (int jj = 0; jj < 4; jj++) {
          unsigned short h = f2bf(acc[m][n][jj] + bs);
          Cb[(size_t)(row + jj) * 3072 + col] = h;
          if (col < NXc) Cq[(size_t)(row + jj) * 2048 + NXc + col] = h;
        }
      } else {
        float bs = bias0[col] + bias1[col];
#pragma unroll
        for (int jj = 0; jj < 4; jj++)
          Cf[(size_t)(row + jj) * NXc + col] = acc[m][n][jj] + bs;
      }
    }
  }
}

// ---------------- flash attention v2: KVBLK=64, 2-phase pipeline, 1 barrier/tile ----
// Block: 64 q-rows (4 waves x 16), qt DESCENDING (heavy blocks dispatch first).
// K double-buffered via global_load_lds with pre-swizzled source (G21).
// V double-buffered: global->reg early (T14), rotation-swizzled LDS write late.
__global__ __launch_bounds__(256) void k_attn(
    const unsigned short* __restrict__ qkv,  // [4096][3072] bf16 (q|k|v)
    const float* __restrict__ adj,           // [2048][2048]
    const unsigned char* __restrict__ tm,    // [32][32] 64x64 tiles
    unsigned short* __restrict__ acat) {
  // K tile: [kv 0..63][16B col 0..7], LDS[row][c] = K_glob[row][c ^ (row&7)]
  __shared__ __align__(16) unsigned short Kb[2][64 * 64];   // 2 x 8 KB
  // V^T tile: row d (72 shorts, 144B, 16B-aligned); short idx = d*72 + ((kv + (d>>3)*8) & 63)
  __shared__ __align__(16) unsigned short Vt[2][64 * 72];   // 2 x 9216 B
  // P per wave: [q 0..15][kv 0..63], row stride 72 shorts (144B)
  __shared__ __align__(16) unsigned short Ps[4][16 * 72];   // 9216 B
  __shared__ int s_kts[33];
  __shared__ unsigned char s_tmv[32];
  __shared__ int s_nkt;

  const int bid = blockIdx.x;
  const int qt = 31 - (bid >> 5);  // heavy-first scheduling
  const int bh = bid & 31;
  const int h = bh & 15;
  const int b = bh >> 4;
  const int q0 = qt * 64;
  const int tid = threadIdx.x;
  const int lane = tid & 63;
  const int w = tid >> 6;
  const int g = lane >> 4, lr = lane & 15;
  const int sc = tid & 7;    // staging 16B col
  const int sr = tid >> 3;   // staging row 0..31

  if (tid == 0) {  // block-uniform active-tile list
    int n = 0;
    for (int kt = 0; kt < 32; kt++) {
      unsigned char v = tm[qt * 32 + kt];
      if (v) { s_kts[n] = kt; s_tmv[n] = v; n++; }
    }
    s_nkt = n;
    s_kts[n] = n ? s_kts[n - 1] : 0;  // clamp for last prefetch
  }

  // Q fragments (A-operand: row=lr, k=8g+j), two D k-slices
  s16x8 qf0, qf1;
  {
    size_t base = (size_t)(b * Tc + q0 + w * 16 + lr) * 3072 + h * 64 + g * 8;
    qf0 = *(const s16x8*)(qkv + base);
    qf1 = *(const s16x8*)(qkv + base + 32);
  }
  f32x4 o[4] = {};
  float mrow[4], lrow[4];
#pragma unroll
  for (int jj = 0; jj < 4; jj++) { mrow[jj] = -1e30f; lrow[jj] = 0.f; }

  __syncthreads();  // s_kts visible
  const int nkt = s_nkt;
  if (nkt == 0) return;  // cannot happen for tril, but safe

  const unsigned short* kbase = qkv + (size_t)(b * Tc) * 3072 + 1024 + h * 64;
  const unsigned short* vbase = kbase + 1024;

  // ---- prologue: stage tile 0 ----
  {
    int kt0 = s_kts[0];
    const unsigned short* kb = kbase + (size_t)kt0 * 64 * 3072;
    gload_lds16(kb + (size_t)sr * 3072 + (sc ^ (sr & 7)) * 8, (void*)(&Kb[0][0] + w * 512));
    gload_lds16(kb + (size_t)(sr + 32) * 3072 + (sc ^ (sr & 7)) * 8,
                (void*)(&Kb[0][0] + 2048 + w * 512));
    const unsigned short* vb = vbase + (size_t)kt0 * 64 * 3072;
    s16x8 v0 = *(const s16x8*)(vb + (size_t)sr * 3072 + sc * 8);
    s16x8 v1 = *(const s16x8*)(vb + (size_t)(sr + 32) * 3072 + sc * 8);
#pragma unroll
    for (int j = 0; j < 8; j++) {
      int d = sc * 8 + j;
      Vt[0][d * 72 + ((sr + sc * 8) & 63)] = (unsigned short)v0[j];
      Vt[0][d * 72 + ((sr + 32 + sc * 8) & 63)] = (unsigned short)v1[j];
    }
  }
  __syncthreads();  // vmcnt(0)+lgkmcnt(0) drained by compiler before barrier

  for (int i = 0; i < nkt; i++) {
    const int cur = i & 1;
    const int kt = s_kts[i];
    const int tmv = s_tmv[i];
    const int kv0 = kt * 64;
    const int nxt = s_kts[i + 1];  // clamped at i==nkt-1 (stages into unread buffer)

    // ---- issue next tile's loads first (latency hides under this tile's compute) ----
    {
      const unsigned short* kb = kbase + (size_t)nxt * 64 * 3072;
      gload_lds16(kb + (size_t)sr * 3072 + (sc ^ (sr & 7)) * 8,
                  (void*)(&Kb[cur ^ 1][0] + w * 512));
      gload_lds16(kb + (size_t)(sr + 32) * 3072 + (sc ^ (sr & 7)) * 8,
                  (void*)(&Kb[cur ^ 1][0] + 2048 + w * 512));
    }
    const unsigned short* vb = vbase + (size_t)nxt * 64 * 3072;
    s16x8 v0 = *(const s16x8*)(vb + (size_t)sr * 3072 + sc * 8);
    s16x8 v1 = *(const s16x8*)(vb + (size_t)(sr + 32) * 3072 + sc * 8);

    // ---- S = Q K^T over 4 kv fragments ----
    f32x4 s[4];
#pragma unroll
    for (int n = 0; n < 4; n++) {
      int kvr = n * 16 + lr;
      const char* kr = (const char*)&Kb[cur][0] + kvr * 128;
      s16x8 b0 = *(const s16x8*)(kr + ((g ^ (kvr & 7)) * 16));
      s16x8 b1 = *(const s16x8*)(kr + (((4 + g) ^ (kvr & 7)) * 16));
      f32x4 z = {};
      z = __builtin_amdgcn_mfma_f32_16x16x32_bf16(qf0, b0, z, 0, 0, 0);
      s[n] = __builtin_amdgcn_mfma_f32_16x16x32_bf16(qf1, b1, z, 0, 0, 0);
    }
    if (tmv != 2) {  // mixed tile: w = s*adj + NEG*(1-adj) (exact for binary adj)
#pragma unroll
      for (int n = 0; n < 4; n++) {
        int col = kv0 + n * 16 + lr;
#pragma unroll
        for (int jj = 0; jj < 4; jj++) {
          float a = adj[(size_t)(q0 + w * 16 + g * 4 + jj) * Tc + col];
          s[n][jj] = a * s[n][jj] + NEGC * (1.0f - a);
        }
      }
    }

    // ---- online softmax (16-lane group reduce; kv col = lr across 4 frags) ----
#pragma unroll
    for (int jj = 0; jj < 4; jj++) {
      float mx = fmaxf(fmaxf(s[0][jj], s[1][jj]), fmaxf(s[2][jj], s[3][jj]));
#pragma unroll
      for (int off = 8; off >= 1; off >>= 1) mx = fmaxf(mx, __shfl_xor(mx, off));
      float mn = fmaxf(mrow[jj], mx);
      float rs = __expf(mrow[jj] - mn);
      mrow[jj] = mn;
      float p0 = __expf(s[0][jj] - mn), p1 = __expf(s[1][jj] - mn);
      float p2 = __expf(s[2][jj] - mn), p3 = __expf(s[3][jj] - mn);
      s[0][jj] = p0; s[1][jj] = p1; s[2][jj] = p2; s[3][jj] = p3;
      float ps = (p0 + p1) + (p2 + p3);
#pragma unroll
      for (int off = 8; off >= 1; off >>= 1) ps += __shfl_xor(ps, off);
      lrow[jj] = lrow[jj] * rs + ps;
#pragma unroll
      for (int nd = 0; nd < 4; nd++) o[nd][jj] *= rs;
    }

    // ---- P -> LDS (per-wave buffer), PV ----
    unsigned short* pw = &Ps[w][0];
#pragma unroll
    for (int n = 0; n < 4; n++)
#pragma unroll
      for (int jj = 0; jj < 4; jj++)
        pw[(g * 4 + jj) * 72 + n * 16 + lr] = f2bf(s[n][jj]);
    s16x8 pa0 = *(const s16x8*)((const char*)pw + lr * 144 + g * 16);
    s16x8 pa1 = *(const s16x8*)((const char*)pw + lr * 144 + 64 + g * 16);
#pragma unroll
    for (int nd = 0; nd < 4; nd++) {
      int d = nd * 16 + lr;
      const char* vrow = (const char*)&Vt[cur][0] + d * 144;
      int swz = (d >> 3) * 8;
      s16x8 vb0 = *(const s16x8*)(vrow + (((8 * g + swz) & 63) * 2));
      s16x8 vb1 = *(const s16x8*)(vrow + (((32 + 8 * g + swz) & 63) * 2));
      o[nd] = __builtin_amdgcn_mfma_f32_16x16x32_bf16(pa0, vb0, o[nd], 0, 0, 0);
      o[nd] = __builtin_amdgcn_mfma_f32_16x16x32_bf16(pa1, vb1, o[nd], 0, 0, 0);
    }

    // ---- late V^T write for next tile (vmcnt on v0/v1 has had the whole tile) ----
    {
      unsigned short* vt = &Vt[cur ^ 1][0];
#pragma unroll
      for (int j = 0; j < 8; j++) {
        int d = sc * 8 + j;
        vt[d * 72 + ((sr + sc * 8) & 63)] = (unsigned short)v0[j];
        vt[d * 72 + ((sr + 32 + sc * 8) & 63)] = (unsigned short)v1[j];
      }
    }
    __syncthreads();  // single barrier per tile: publishes K/V^T(next), fences buf reuse
  }

#pragma unroll
  for (int jj = 0; jj < 4; jj++) {
    float inv = lrow[jj] > 0.f ? 1.0f / lrow[jj] : 0.f;
    size_t m = (size_t)(b * Tc + q0 + w * 16 + g * 4 + jj);
#pragma unroll
    for (int nd = 0; nd < 4; nd++)
      acat[m * 2048 + h * 64 + nd * 16 + lr] = f2bf(o[nd][jj] * inv);
  }
}

extern "C" void kernel_launch(void* const* d_in, const int* in_sizes, int n_in,
                              void* d_out, int out_size, void* d_ws, size_t ws_size,
                              hipStream_t stream) {
  const float* x       = (const float*)d_in[0];
  const float* adj     = (const float*)d_in[1];
  const float* w_attn  = (const float*)d_in[2];
  const float* b_attn  = (const float*)d_in[3];
  const float* w_proj  = (const float*)d_in[4];
  const float* b_proj  = (const float*)d_in[5];
  const float* w_proj1 = (const float*)d_in[6];
  const float* b_proj1 = (const float*)d_in[7];
  float* out = (float*)d_out;

  char* ws = (char*)d_ws;
  size_t off = 0;
  unsigned short* xb     = (unsigned short*)(ws + off); off += (size_t)4096 * 1024 * 2;
  unsigned short* wattnT = (unsigned short*)(ws + off); off += (size_t)3072 * 1024 * 2;
  unsigned short* wcatT  = (unsigned short*)(ws + off); off += (size_t)1024 * 2048 * 2;
  unsigned short* qkv    = (unsigned short*)(ws + off); off += (size_t)4096 * 3072 * 2;
  unsigned short* acat   = (unsigned short*)(ws + off); off += (size_t)4096 * 2048 * 2;
  unsigned char*  tmask  = (unsigned char*)(ws + off);  off += 1024;
  (void)ws_size; (void)in_sizes; (void)n_in; (void)out_size;

  k_cvt_x<<<4096, 256, 0, stream>>>(x, xb);
  k_transpose_bf16<<<dim3(96, 32), 256, 0, stream>>>(w_attn, 1024, 3072, wattnT, 1024, 0);
  k_transpose_bf16<<<dim3(32, 32), 256, 0, stream>>>(w_proj, 1024, 1024, wcatT, 2048, 0);
  k_transpose_bf16<<<dim3(32, 32), 256, 0, stream>>>(w_proj1, 1024, 1024, wcatT, 2048, 1024);
  k_tilemask<<<dim3(32, 32), 256, 0, stream>>>(adj, tmask);
  k_gemm_bt<0><<<dim3(24, 32), 256, 0, stream>>>(xb, wattnT, 1024, b_attn, nullptr,
                                                 qkv, acat, nullptr);
  k_attn<<<1024, 256, 0, stream>>>(qkv, adj, tmask, acat);
  k_gemm_bt<1><<<dim3(8, 32), 256, 0, stream>>>(acat, wcatT, 2048, b_proj, b_proj1,
                                                nullptr, nullptr, out);
}

// Round 4
// 167.887 us; speedup vs baseline: 1.6628x; 1.0718x over previous
//
#include <hip/hip_runtime.h>
#include <stdint.h>

typedef short s16x8 __attribute__((ext_vector_type(8)));
typedef float f32x4 __attribute__((ext_vector_type(4)));

#define AS1 __attribute__((address_space(1)))
#define AS3 __attribute__((address_space(3)))

static constexpr int Bc = 2, Tc = 2048, NXc = 1024, Hc = 16;
static constexpr float NEGC = -1e9f;

static __device__ __forceinline__ unsigned short f2bf(float f) {
  uint32_t u = __builtin_bit_cast(uint32_t, f);
  u += 0x7fffu + ((u >> 16) & 1u);
  return (unsigned short)(u >> 16);
}

static __device__ __forceinline__ void gload_lds16(const void* g, void* l) {
  __builtin_amdgcn_global_load_lds((const AS1 uint32_t*)g, (AS3 uint32_t*)l, 16, 0, 0);
}

// ---------------- prep: x -> bf16 ----------------
__global__ __launch_bounds__(256) void k_cvt_x(const float* __restrict__ x,
                                               unsigned short* __restrict__ xb) {
  int i = blockIdx.x * blockDim.x + threadIdx.x;
  float4 v = ((const float4*)x)[i];
  uint32_t lo = (uint32_t)f2bf(v.x) | ((uint32_t)f2bf(v.y) << 16);
  uint32_t hi = (uint32_t)f2bf(v.z) | ((uint32_t)f2bf(v.w) << 16);
  ((uint2*)xb)[i] = make_uint2(lo, hi);
}

// ---------------- prep: transpose f32 [K][N] -> bf16 [N][dld] at col offset dkoff ----
__global__ __launch_bounds__(256) void k_transpose_bf16(
    const float* __restrict__ src, int srows, int scols,
    unsigned short* __restrict__ dst, int dld, int dkoff) {
  __shared__ float tile[32][33];
  int n0 = blockIdx.x * 32, k0 = blockIdx.y * 32;
  int tx = threadIdx.x & 31, ty = threadIdx.x >> 5;
#pragma unroll
  for (int r = 0; r < 4; r++)
    tile[ty + r * 8][tx] = src[(size_t)(k0 + ty + r * 8) * scols + n0 + tx];
  __syncthreads();
#pragma unroll
  for (int r = 0; r < 4; r++) {
    int n = n0 + ty + r * 8;
    dst[(size_t)n * dld + dkoff + k0 + tx] = f2bf(tile[tx][ty + r * 8]);
  }
}

// ---------------- prep: adjacency 64x64 tile classifier ----------------
__global__ __launch_bounds__(256) void k_tilemask(const float* __restrict__ adj,
                                                  unsigned char* __restrict__ tm) {
  int kt = blockIdx.x, qt = blockIdx.y;
  int t = threadIdx.x;
  bool anyv = false, all1 = true;
#pragma unroll
  for (int i = 0; i < 4; i++) {
    int e = t * 4 + i;
    int row = e >> 4, c4 = e & 15;
    float4 v = *(const float4*)&adj[(size_t)(qt * 64 + row) * Tc + kt * 64 + c4 * 4];
    anyv |= (v.x != 0.f) | (v.y != 0.f) | (v.z != 0.f) | (v.w != 0.f);
    all1 &= (v.x == 1.f) & (v.y == 1.f) & (v.z == 1.f) & (v.w == 1.f);
  }
  __shared__ int s_any, s_all;
  if (t == 0) { s_any = 0; s_all = 1; }
  __syncthreads();
  if (anyv) s_any = 1;
  if (!all1) s_all = 0;
  __syncthreads();
  if (t == 0) tm[qt * 32 + kt] = (unsigned char)(s_any ? (s_all ? 2 : 1) : 0);
}

// ---------------- bf16 GEMM, B^T layout, split-K A source ----------------
// A rows come from A (k < ksplit, stride lda) or A2 (k >= ksplit, stride lda2).
// MODE 0: C -> Cb bf16 [M][3072] (+bias0).  MODE 1: C -> Cf f32 [M][1024] (+bias0+bias1)
template <int MODE>
__global__ __launch_bounds__(256) void k_gemm_bt(
    const unsigned short* __restrict__ A, int lda,
    const unsigned short* __restrict__ A2, int lda2, int ksplit,
    const unsigned short* __restrict__ BT, int K,
    const float* __restrict__ bias0, const float* __restrict__ bias1,
    unsigned short* __restrict__ Cb, float* __restrict__ Cf) {
  __shared__ __align__(16) unsigned short As[128 * 32];
  __shared__ __align__(16) unsigned short Bs[128 * 32];
  const int lane = threadIdx.x & 63;
  const int w = threadIdx.x >> 6;
  const int m0 = blockIdx.y * 128;
  const int n0 = blockIdx.x * 128;
  const int wr = (w >> 1) * 64;
  const int wc = (w & 1) * 64;
  const int g = lane >> 4, lr = lane & 15;
  const int srow = lane >> 2;
  const int scol = lane & 3;
  f32x4 acc[4][4] = {};

  for (int k0 = 0; k0 < K; k0 += 32) {
    __syncthreads();
#pragma unroll
    for (int i = 0; i < 2; i++) {
      int c = w * 2 + i;
      int row = c * 16 + srow;
      int cs = scol ^ (row & 3);
      const unsigned short* ap;
      if (k0 < ksplit) ap = A + (size_t)(m0 + row) * lda + k0;
      else             ap = A2 + (size_t)(m0 + row) * lda2 + (k0 - ksplit);
      gload_lds16(ap + cs * 8, (void*)(As + c * 512));
      gload_lds16(BT + (size_t)(n0 + row) * K + k0 + cs * 8, (void*)(Bs + c * 512));
    }
    __syncthreads();
    s16x8 af[4], bfr[4];
#pragma unroll
    for (int m = 0; m < 4; m++) {
      int row = wr + m * 16 + lr;
      af[m] = *(const s16x8*)((const char*)As + row * 64 + ((g ^ (row & 3)) * 16));
    }
#pragma unroll
    for (int n = 0; n < 4; n++) {
      int row = wc + n * 16 + lr;
      bfr[n] = *(const s16x8*)((const char*)Bs + row * 64 + ((g ^ (row & 3)) * 16));
    }
#pragma unroll
    for (int m = 0; m < 4; m++)
#pragma unroll
      for (int n = 0; n < 4; n++)
        acc[m][n] = __builtin_amdgcn_mfma_f32_16x16x32_bf16(af[m], bfr[n], acc[m][n], 0, 0, 0);
  }

#pragma unroll
  for (int m = 0; m < 4; m++) {
    int row = m0 + wr + m * 16 + g * 4;
#pragma unroll
    for (int n = 0; n < 4; n++) {
      int col = n0 + wc + n * 16 + lr;
      if (MODE == 0) {
        float bs = bias0[col];
#pragma unroll
        for (int jj = 0; jj < 4; jj++)
          Cb[(size_t)(row + jj) * 3072 + col] = f2bf(acc[m][n][jj] + bs);
      } else {
        float bs = bias0[col] + bias1[col];
#pragma unroll
        for (int jj = 0; jj < 4; jj++)
          Cf[(size_t)(row + jj) * NXc + col] = acc[m][n][jj] + bs;
      }
    }
  }
}

// ---------------- flash attention v3: swapped QK^T -> lane-local softmax ----------------
// S^T = mfma(A=K, B=Q): lane (col=q=lane&15, grp g) holds S[kv=16n+4g+r][q] -> each lane
// owns all 64 kv scores of ONE q row => softmax reduce = tree + 2 shfl_xor (16,32).
__global__ __launch_bounds__(256) void k_attn(
    const unsigned short* __restrict__ qkv,  // [4096][3072] bf16 (q|k|v)
    const float* __restrict__ adj,           // [2048][2048]
    const unsigned char* __restrict__ tm,    // [32][32] 64x64 tiles
    unsigned short* __restrict__ acat) {     // [4096][1024] bf16
  __shared__ __align__(16) unsigned short Kb[2][64 * 64];   // [kv][16B-gran ^ (kv&7)]
  __shared__ __align__(16) unsigned short Vt[2][64 * 72];   // d*72 + ((kv + (d>>3)*8)&63)
  __shared__ __align__(16) unsigned short Ps[4][16 * 64];   // per-wave [q][16B-gran ^ (q&7)]
  __shared__ int s_kts[33];
  __shared__ unsigned char s_tmv[32];
  __shared__ int s_nkt;

  const int bid = blockIdx.x;
  const int qt = 31 - (bid >> 5);  // heavy-first
  const int bh = bid & 31;
  const int h = bh & 15;
  const int b = bh >> 4;
  const int q0 = qt * 64;
  const int tid = threadIdx.x;
  const int lane = tid & 63;
  const int w = tid >> 6;
  const int g = lane >> 4, lr = lane & 15;
  const int sc = tid & 7;
  const int sr = tid >> 3;

  if (tid == 0) {
    int n = 0;
    for (int kt = 0; kt < 32; kt++) {
      unsigned char v = tm[qt * 32 + kt];
      if (v) { s_kts[n] = kt; s_tmv[n] = v; n++; }
    }
    s_nkt = n;
    s_kts[n] = n ? s_kts[n - 1] : 0;
  }

  // Q fragment registers serve as the mfma B-operand (identical lane map): col=q=lr, d=8g+j
  s16x8 qf0, qf1;
  {
    size_t base = (size_t)(b * Tc + q0 + w * 16 + lr) * 3072 + h * 64 + g * 8;
    qf0 = *(const s16x8*)(qkv + base);
    qf1 = *(const s16x8*)(qkv + base + 32);
  }
  f32x4 o[4] = {};
  float mrow = -1e30f, lrow = 0.f;  // single (m,l) per lane: the lane's q row

  __syncthreads();
  const int nkt = s_nkt;
  if (nkt == 0) return;

  const unsigned short* kbase = qkv + (size_t)(b * Tc) * 3072 + 1024 + h * 64;
  const unsigned short* vbase = kbase + 1024;

  // ---- prologue: stage tile 0 ----
  {
    int kt0 = s_kts[0];
    const unsigned short* kb = kbase + (size_t)kt0 * 64 * 3072;
    gload_lds16(kb + (size_t)sr * 3072 + (sc ^ (sr & 7)) * 8, (void*)(&Kb[0][0] + w * 512));
    gload_lds16(kb + (size_t)(sr + 32) * 3072 + (sc ^ (sr & 7)) * 8,
                (void*)(&Kb[0][0] + 2048 + w * 512));
    const unsigned short* vb = vbase + (size_t)kt0 * 64 * 3072;
    s16x8 v0 = *(const s16x8*)(vb + (size_t)sr * 3072 + sc * 8);
    s16x8 v1 = *(const s16x8*)(vb + (size_t)(sr + 32) * 3072 + sc * 8);
#pragma unroll
    for (int j = 0; j < 8; j++) {
      int d = sc * 8 + j;
      Vt[0][d * 72 + ((sr + sc * 8) & 63)] = (unsigned short)v0[j];
      Vt[0][d * 72 + ((sr + 32 + sc * 8) & 63)] = (unsigned short)v1[j];
    }
  }
  __syncthreads();

  for (int i = 0; i < nkt; i++) {
    const int cur = i & 1;
    const int kt = s_kts[i];
    const int tmv = s_tmv[i];
    const int kv0 = kt * 64;
    const int nxt = s_kts[i + 1];

    // ---- prefetch next tile (K direct-to-LDS, V to regs) ----
    {
      const unsigned short* kb = kbase + (size_t)nxt * 64 * 3072;
      gload_lds16(kb + (size_t)sr * 3072 + (sc ^ (sr & 7)) * 8,
                  (void*)(&Kb[cur ^ 1][0] + w * 512));
      gload_lds16(kb + (size_t)(sr + 32) * 3072 + (sc ^ (sr & 7)) * 8,
                  (void*)(&Kb[cur ^ 1][0] + 2048 + w * 512));
    }
    const unsigned short* vb = vbase + (size_t)nxt * 64 * 3072;
    s16x8 v0 = *(const s16x8*)(vb + (size_t)sr * 3072 + sc * 8);
    s16x8 v1 = *(const s16x8*)(vb + (size_t)(sr + 32) * 3072 + sc * 8);

    // ---- S^T = K Q (A=K rows, B=Q cols) ----
    f32x4 s[4];
    __builtin_amdgcn_s_setprio(1);
#pragma unroll
    for (int n = 0; n < 4; n++) {
      int kvr = n * 16 + lr;
      const char* kr = (const char*)&Kb[cur][0] + kvr * 128;
      s16x8 a0 = *(const s16x8*)(kr + ((g ^ (kvr & 7)) * 16));
      s16x8 a1 = *(const s16x8*)(kr + (((4 + g) ^ (kvr & 7)) * 16));
      f32x4 z = {};
      z = __builtin_amdgcn_mfma_f32_16x16x32_bf16(a0, qf0, z, 0, 0, 0);
      s[n] = __builtin_amdgcn_mfma_f32_16x16x32_bf16(a1, qf1, z, 0, 0, 0);
    }
    __builtin_amdgcn_s_setprio(0);

    if (tmv != 2) {  // mixed tile: w = s*adj + NEG*(1-adj); kv is the in-lane fast axis
      const float* arow = adj + (size_t)(q0 + w * 16 + lr) * Tc + kv0;
#pragma unroll
      for (int n = 0; n < 4; n++) {
        float4 a = *(const float4*)(arow + n * 16 + 4 * g);
        s[n][0] = a.x * s[n][0] + NEGC * (1.0f - a.x);
        s[n][1] = a.y * s[n][1] + NEGC * (1.0f - a.y);
        s[n][2] = a.z * s[n][2] + NEGC * (1.0f - a.z);
        s[n][3] = a.w * s[n][3] + NEGC * (1.0f - a.w);
      }
    }

    // ---- lane-local online softmax (q = lane's own row) ----
    float mx = -1e30f;
#pragma unroll
    for (int n = 0; n < 4; n++)
#pragma unroll
      for (int r = 0; r < 4; r++) mx = fmaxf(mx, s[n][r]);
    mx = fmaxf(mx, __shfl_xor(mx, 16));
    mx = fmaxf(mx, __shfl_xor(mx, 32));
    const bool noresc = __all(mx <= mrow + 8.f);  // defer-max (T13), wave-uniform
    float rs = 1.f;
    if (!noresc) {
      float mn = fmaxf(mrow, mx);
      rs = __expf(mrow - mn);
      mrow = mn;
    }
    float ps = 0.f;
#pragma unroll
    for (int n = 0; n < 4; n++)
#pragma unroll
      for (int r = 0; r < 4; r++) {
        float p = __expf(s[n][r] - mrow);
        s[n][r] = p;
        ps += p;
      }
    ps += __shfl_xor(ps, 16);
    ps += __shfl_xor(ps, 32);
    if (!noresc) {
      lrow = lrow * rs + ps;
#pragma unroll
      for (int jj = 0; jj < 4; jj++) {
        float r4 = __shfl(rs, 4 * g + jj);  // rescale factor for o-row q=4g+jj
#pragma unroll
        for (int nd = 0; nd < 4; nd++) o[nd][jj] *= r4;
      }
    } else {
      lrow += ps;
    }

    // ---- P -> LDS: 8 packed b32 writes into swizzled [q][64] row ----
    {
      char* prow = (char*)&Ps[w][0] + lr * 128;
#pragma unroll
      for (int n = 0; n < 4; n++) {
        uint32_t w0 = (uint32_t)f2bf(s[n][0]) | ((uint32_t)f2bf(s[n][1]) << 16);
        uint32_t w1 = (uint32_t)f2bf(s[n][2]) | ((uint32_t)f2bf(s[n][3]) << 16);
        char* base = prow + (((2 * n + (g >> 1)) ^ (lr & 7)) * 16) + 8 * (g & 1);
        *(uint32_t*)base = w0;
        *(uint32_t*)(base + 4) = w1;
      }
    }
    const char* prow = (const char*)&Ps[w][0] + lr * 128;
    s16x8 pa0 = *(const s16x8*)(prow + ((g ^ (lr & 7)) * 16));
    s16x8 pa1 = *(const s16x8*)(prow + (((4 + g) ^ (lr & 7)) * 16));
    __builtin_amdgcn_s_setprio(1);
#pragma unroll
    for (int nd = 0; nd < 4; nd++) {
      int d = nd * 16 + lr;
      const char* vrow = (const char*)&Vt[cur][0] + d * 144;
      int swz = (d >> 3) * 8;
      s16x8 vb0 = *(const s16x8*)(vrow + (((8 * g + swz) & 63) * 2));
      s16x8 vb1 = *(const s16x8*)(vrow + (((32 + 8 * g + swz) & 63) * 2));
      o[nd] = __builtin_amdgcn_mfma_f32_16x16x32_bf16(pa0, vb0, o[nd], 0, 0, 0);
      o[nd] = __builtin_amdgcn_mfma_f32_16x16x32_bf16(pa1, vb1, o[nd], 0, 0, 0);
    }
    __builtin_amdgcn_s_setprio(0);

    // ---- late V^T write for next tile ----
    {
      unsigned short* vt = &Vt[cur ^ 1][0];
#pragma unroll
      for (int j = 0; j < 8; j++) {
        int d = sc * 8 + j;
        vt[d * 72 + ((sr + sc * 8) & 63)] = (unsigned short)v0[j];
        vt[d * 72 + ((sr + 32 + sc * 8) & 63)] = (unsigned short)v1[j];
      }
    }
    __syncthreads();
  }

  float inv = lrow > 0.f ? 1.0f / lrow : 0.f;
#pragma unroll
  for (int jj = 0; jj < 4; jj++) {
    float iv = __shfl(inv, 4 * g + jj);  // denom for o-row q=4g+jj
    size_t m = (size_t)(b * Tc + q0 + w * 16 + g * 4 + jj);
#pragma unroll
    for (int nd = 0; nd < 4; nd++)
      acat[m * 1024 + h * 64 + nd * 16 + lr] = f2bf(o[nd][jj] * iv);
  }
}

extern "C" void kernel_launch(void* const* d_in, const int* in_sizes, int n_in,
                              void* d_out, int out_size, void* d_ws, size_t ws_size,
                              hipStream_t stream) {
  const float* x       = (const float*)d_in[0];
  const float* adj     = (const float*)d_in[1];
  const float* w_attn  = (const float*)d_in[2];
  const float* b_attn  = (const float*)d_in[3];
  const float* w_proj  = (const float*)d_in[4];
  const float* b_proj  = (const float*)d_in[5];
  const float* w_proj1 = (const float*)d_in[6];
  const float* b_proj1 = (const float*)d_in[7];
  float* out = (float*)d_out;

  char* ws = (char*)d_ws;
  size_t off = 0;
  unsigned short* xb     = (unsigned short*)(ws + off); off += (size_t)4096 * 1024 * 2;
  unsigned short* wattnT = (unsigned short*)(ws + off); off += (size_t)3072 * 1024 * 2;
  unsigned short* wcatT  = (unsigned short*)(ws + off); off += (size_t)1024 * 2048 * 2;
  unsigned short* qkv    = (unsigned short*)(ws + off); off += (size_t)4096 * 3072 * 2;
  unsigned short* acat   = (unsigned short*)(ws + off); off += (size_t)4096 * 1024 * 2;
  unsigned char*  tmask  = (unsigned char*)(ws + off);  off += 1024;
  (void)ws_size; (void)in_sizes; (void)n_in; (void)out_size;

  k_cvt_x<<<4096, 256, 0, stream>>>(x, xb);
  k_transpose_bf16<<<dim3(96, 32), 256, 0, stream>>>(w_attn, 1024, 3072, wattnT, 1024, 0);
  k_transpose_bf16<<<dim3(32, 32), 256, 0, stream>>>(w_proj, 1024, 1024, wcatT, 2048, 0);
  k_transpose_bf16<<<dim3(32, 32), 256, 0, stream>>>(w_proj1, 1024, 1024, wcatT, 2048, 1024);
  k_tilemask<<<dim3(32, 32), 256, 0, stream>>>(adj, tmask);
  // qkv = x @ w_attn + b_attn
  k_gemm_bt<0><<<dim3(24, 32), 256, 0, stream>>>(xb, 1024, xb, 1024, 1024,
                                                 wattnT, 1024, b_attn, nullptr,
                                                 qkv, nullptr);
  // attention -> acat [4096][1024]
  k_attn<<<1024, 256, 0, stream>>>(qkv, adj, tmask, acat);
  // out = [a | q] @ [w_proj ; w_proj1]: A = acat for k<1024, q (qkv cols 0..1023) for k>=1024
  k_gemm_bt<1><<<dim3(8, 32), 256, 0, stream>>>(acat, 1024, qkv, 3072, 1024,
                                                wcatT, 2048, b_proj, b_proj1,
                                                nullptr, out);
}